// Round 10
// baseline (1165.715 us; speedup 1.0000x reference)
//
#include <hip/hip_runtime.h>
#include <cstdint>

typedef __attribute__((ext_vector_type(8))) __bf16 bf16x8;
typedef __attribute__((ext_vector_type(4))) float f32x4;
typedef __attribute__((ext_vector_type(4))) unsigned int uint4v;
typedef __attribute__((ext_vector_type(2))) unsigned int uint2v;
typedef __attribute__((ext_vector_type(4))) float float4v;
typedef __attribute__((ext_vector_type(2))) long long2v;

__device__ __forceinline__ unsigned short f2bf(float x){
  union { float f; unsigned u; } v; v.f = x;
  unsigned r = v.u + 0x7FFFu + ((v.u >> 16) & 1u);
  return (unsigned short)(r >> 16);
}
__device__ __forceinline__ float bf2f(unsigned short h){
  union { unsigned u; float f; } v; v.u = ((unsigned)h) << 16;
  return v.f;
}
__device__ __forceinline__ float bflo(unsigned u){
  union { unsigned x; float f; } v; v.x = u << 16; return v.f;
}
__device__ __forceinline__ float bfhi(unsigned u){
  union { unsigned x; float f; } v; v.x = u & 0xFFFF0000u; return v.f;
}
__device__ __forceinline__ f32x4 MFMA16(bf16x8 a, bf16x8 b, f32x4 c){
  return __builtin_amdgcn_mfma_f32_16x16x32_bf16(a, b, c, 0, 0, 0);
}
__device__ __forceinline__ f32x4 MFMA8(long a, long b, f32x4 c){
  return __builtin_amdgcn_mfma_f32_16x16x32_fp8_fp8(a, b, c, 0, 0, 0);
}
__device__ __forceinline__ unsigned char f2fp8(float x){
  int p = __builtin_amdgcn_cvt_pk_fp8_f32(x, x, 0, false);
  return (unsigned char)(p & 0xFF);
}

// ---------------- prep ----------------
// wfrag8 (fp8 e4m3, value = fp8(16*W)): byte idx = (((w*4+kkp)*6+mg)*64 + l)*16 + ks*8 + e
//   kk = kkp*2+ks ; mg: 0=ihR 1=ihZ 2=ihN 3=hhR 4=hhZ 5=hhN
//   n = g*256 + w*16 + (l&15), k = kk*32 + (l>>4)*8 + e
// mlpfrag bf16: idx = w*512 + l*8 + e; n = w*16+(l&15), k = (l>>4)*8+e (k>=16 -> 0)
__global__ __launch_bounds__(256) void prep_k(
    const float* __restrict__ wih, const float* __restrict__ whh,
    const float* __restrict__ wl, const float* __restrict__ wr,
    const float* __restrict__ bl, const float* __restrict__ br,
    const float* __restrict__ fcw, const float* __restrict__ mlpw,
    unsigned char* __restrict__ wfrag8, unsigned short* __restrict__ mlpfrag,
    unsigned short* __restrict__ wlrT, unsigned short* __restrict__ fcwT,
    float* __restrict__ blbr){
  int i = blockIdx.x*256 + threadIdx.x;
  if (i < 393216){
    int b16 = i & 15;
    int l   = (i >> 4) & 63;
    int chunk = i >> 10;           // (w*4+kkp)*6+mg
    int wkp = chunk / 6;
    int mg  = chunk - 6*wkp;
    int w = wkp >> 2, kkp = wkp & 3;
    int ks = b16 >> 3, e = b16 & 7;
    int kk = kkp*2 + ks;
    int mat = mg / 3, g = mg - 3*(mg/3);
    int n = g*256 + w*16 + (l & 15);
    int k = kk*32 + (l >> 4)*8 + e;
    float v = 16.f * (mat ? whh[n*256 + k] : wih[n*256 + k]);
    wfrag8[i] = f2fp8(v);
    return;
  }
  i -= 393216;
  if (i < 8192){
    int w = i >> 9;
    int r4 = i & 511;
    int l = r4 >> 3, e = r4 & 7;
    int n = w*16 + (l & 15);
    int k = (l >> 4)*8 + e;
    mlpfrag[i] = (k < 16) ? f2bf(mlpw[k*256 + n]) : (unsigned short)0;
    return;
  }
  i -= 8192;
  if (i < 655360){
    int n = i >> 8, k = i & 255;
    float v = (n < 1280) ? wl[k*1280 + n] : wr[k*1280 + (n-1280)];
    wlrT[i] = f2bf(v); return;
  }
  i -= 655360;
  if (i < 802816){
    int n = i / 3136, k = i - n*3136;
    fcwT[i] = f2bf(fcw[k*256 + n]); return;
  }
  i -= 802816;
  if (i < 2560){
    blbr[i] = (i < 1280) ? bl[i] : br[i-1280];
  }
}

// ---------------- conv1: [256,3,84,84] -> bf16 [256,32,20,20], s=4 k=8, relu ----
__global__ __launch_bounds__(256) void conv1_k(const float* __restrict__ in,
              const float* __restrict__ w, const float* __restrict__ bias,
              unsigned short* __restrict__ out){
  __shared__ float in_s[3][24][84];
  __shared__ float w_s[32][3][8][8];
  __shared__ float b_s[32];
  int bid = blockIdx.x; int b = bid >> 2, q = bid & 3;
  int t = threadIdx.x;
  for (int idx = t; idx < 3*24*84; idx += 256){
    int ic = idx / (24*84); int rem = idx - ic*(24*84);
    int iy = rem / 84, ix = rem - iy*84;
    in_s[ic][iy][ix] = in[((size_t)(b*3+ic)*84 + (q*20 + iy))*84 + ix];
  }
  for (int idx = t; idx < 32*192; idx += 256) ((float*)w_s)[idx] = w[idx];
  if (t < 32) b_s[t] = bias[t];
  __syncthreads();
  for (int p = t; p < 800; p += 256){
    int oc = p / 25; int rem = p - oc*25;
    int oy = rem / 5, og = rem - oy*5;
    float a0=b_s[oc],a1=b_s[oc],a2=b_s[oc],a3=b_s[oc];
    #pragma unroll
    for (int ic=0;ic<3;ic++){
      #pragma unroll
      for (int ky=0;ky<8;ky++){
        const float* row = &in_s[ic][oy*4+ky][og*16];
        float s[20];
        #pragma unroll
        for (int cc=0;cc<20;cc++) s[cc]=row[cc];
        const float* wp = &w_s[oc][ic][ky][0];
        #pragma unroll
        for (int kx=0;kx<8;kx++){
          float wv = wp[kx];
          a0 += s[kx]*wv; a1 += s[4+kx]*wv; a2 += s[8+kx]*wv; a3 += s[12+kx]*wv;
        }
      }
    }
    size_t ob = ((size_t)(b*32+oc)*20 + (q*5+oy))*20 + og*4;
    out[ob+0]=f2bf(fmaxf(a0,0.f)); out[ob+1]=f2bf(fmaxf(a1,0.f));
    out[ob+2]=f2bf(fmaxf(a2,0.f)); out[ob+3]=f2bf(fmaxf(a3,0.f));
  }
}

// ---------------- conv2: bf16 [256,32,20,20] -> bf16 [256,64,9,9], s=2 k=4 ----
__global__ __launch_bounds__(256) void conv2_k(const unsigned short* __restrict__ in,
              const float* __restrict__ w, const float* __restrict__ bias,
              unsigned short* __restrict__ out){
  __shared__ unsigned short in_s[32][20][20];
  __shared__ float w_s[16][32][4][4];
  __shared__ float b_s[16];
  int bid = blockIdx.x; int b = bid >> 2, h = bid & 3;
  int t = threadIdx.x;
  for (int idx = t; idx < 32*400; idx += 256) ((unsigned short*)in_s)[idx] = in[(size_t)b*12800 + idx];
  for (int idx = t; idx < 16*512; idx += 256) ((float*)w_s)[idx] = w[h*8192 + idx];
  if (t < 16) b_s[t] = bias[h*16 + t];
  __syncthreads();
  for (int p = t; p < 432; p += 256){
    int ocl = p / 27; int rem = p - ocl*27;
    int oy = rem / 3, og = rem - oy*3;
    float a0=b_s[ocl],a1=b_s[ocl],a2=b_s[ocl];
    #pragma unroll 4
    for (int ic=0;ic<32;ic++){
      #pragma unroll
      for (int ky=0;ky<4;ky++){
        const unsigned short* row = &in_s[ic][oy*2+ky][og*6];
        float s[8];
        #pragma unroll
        for (int cc=0;cc<8;cc++) s[cc]=bf2f(row[cc]);
        const float* wp = &w_s[ocl][ic][ky][0];
        #pragma unroll
        for (int kx=0;kx<4;kx++){
          float wv = wp[kx];
          a0 += s[kx]*wv; a1 += s[2+kx]*wv; a2 += s[4+kx]*wv;
        }
      }
    }
    size_t ob = ((size_t)(b*64 + h*16+ocl)*9 + oy)*9 + og*3;
    out[ob+0]=f2bf(fmaxf(a0,0.f)); out[ob+1]=f2bf(fmaxf(a1,0.f)); out[ob+2]=f2bf(fmaxf(a2,0.f));
  }
}

// ---------------- conv3: bf16 [256,64,9,9] -> bf16 [256,3136] (flat NCHW), s=1 k=3 ----
__global__ __launch_bounds__(256) void conv3_k(const unsigned short* __restrict__ in,
              const float* __restrict__ w, const float* __restrict__ bias,
              unsigned short* __restrict__ out){
  __shared__ unsigned short in_s[64][9][9];
  __shared__ float w_s[16][64][3][3];
  __shared__ float b_s[16];
  int bid = blockIdx.x; int b = bid >> 2, h = bid & 3;
  int t = threadIdx.x;
  for (int idx = t; idx < 64*81; idx += 256) ((unsigned short*)in_s)[idx] = in[(size_t)b*5184 + idx];
  for (int idx = t; idx < 16*576; idx += 256) ((float*)w_s)[idx] = w[h*9216 + idx];
  if (t < 16) b_s[t] = bias[h*16 + t];
  __syncthreads();
  for (int p = t; p < 224; p += 256){
    int ocl = p / 14; int rem = p - ocl*14;
    int oy = rem >> 1, og = rem & 1;
    int ox0 = og*4; int nx = og ? 3 : 4;
    float a[4]; a[0]=a[1]=a[2]=a[3]=b_s[ocl];
    for (int ic=0;ic<64;ic++){
      #pragma unroll
      for (int ky=0;ky<3;ky++){
        const unsigned short* row = &in_s[ic][oy+ky][ox0];
        float s[6];
        #pragma unroll
        for (int cc=0;cc<6;cc++) s[cc] = (ox0+cc < 9) ? bf2f(row[cc]) : 0.f;
        const float* wp = &w_s[ocl][ic][ky][0];
        #pragma unroll
        for (int kx=0;kx<3;kx++){
          float wv = wp[kx];
          #pragma unroll
          for (int jj=0;jj<4;jj++) a[jj] += s[jj+kx]*wv;
        }
      }
    }
    size_t ob = (size_t)b*3136 + (h*16+ocl)*49 + oy*7 + ox0;
    #pragma unroll
    for (int jj=0;jj<4;jj++) if (jj < nx) out[ob+jj] = f2bf(fmaxf(a[jj],0.f));
  }
}

// ---------------- generic MFMA GEMM: C[m,n] = act(A[m,:]·B[n,:] + bias[n]) ----
__global__ __launch_bounds__(256) void gemm_k(const unsigned short* __restrict__ A,
              const unsigned short* __restrict__ B, const float* __restrict__ bias,
              unsigned short* __restrict__ C, int K, int ldc, int rowmul, int relu, int Nblk){
  __shared__ __align__(16) unsigned short As[64*32];
  __shared__ __align__(16) unsigned short Bs[64*32];
  int bid = blockIdx.x;
  int nb = bid % Nblk, mb = bid / Nblk;
  int t = threadIdx.x;
  int w = t >> 6, l = t & 63, lr = l & 15, lh = l >> 4;
  int sr = t >> 2, sq = t & 3;
  f32x4 acc[4];
  #pragma unroll
  for (int i=0;i<4;i++) acc[i] = (f32x4){0.f,0.f,0.f,0.f};
  int nkk = K >> 5;
  const size_t a_row = (size_t)(mb*64 + sr)*K;
  const size_t b_row = (size_t)(nb*64 + sr)*K;
  for (int kk=0;kk<nkk;kk++){
    uint4v av = *(const uint4v*)&A[a_row + kk*32 + sq*8];
    uint4v bv = *(const uint4v*)&B[b_row + kk*32 + sq*8];
    __syncthreads();
    *(uint4v*)((char*)As + ((sr*64 + sq*16) ^ ((sr&3)<<4))) = av;
    *(uint4v*)((char*)Bs + ((sr*64 + sq*16) ^ ((sr&3)<<4))) = bv;
    __syncthreads();
    int brow = w*16 + lr;
    bf16x8 bfr = *(const bf16x8*)((char*)Bs + ((brow*64 + lh*16) ^ ((brow&3)<<4)));
    #pragma unroll
    for (int mt=0;mt<4;mt++){
      int arow = mt*16 + lr;
      bf16x8 afr = *(const bf16x8*)((char*)As + ((arow*64 + lh*16) ^ ((arow&3)<<4)));
      acc[mt] = MFMA16(afr, bfr, acc[mt]);
    }
  }
  int col = nb*64 + w*16 + lr;
  float bn = bias[col];
  #pragma unroll
  for (int mt=0;mt<4;mt++){
    #pragma unroll
    for (int r=0;r<4;r++){
      int row = mb*64 + mt*16 + lh*4 + r;
      float v = acc[mt][r] + bn;
      if (relu) v = fmaxf(v, 0.f);
      C[(size_t)row*rowmul*ldc + col] = f2bf(v);
    }
  }
}

// ---------------- FC split-K GEMM: 112 blocks = 16 tiles x 7 K-slices, f32 partials ----
__global__ __launch_bounds__(256) void gemm_fc_k(const unsigned short* __restrict__ A,
              const unsigned short* __restrict__ B, float* __restrict__ P){
  __shared__ __align__(16) unsigned short As[64*32];
  __shared__ __align__(16) unsigned short Bs[64*32];
  int bid = blockIdx.x;
  int s = bid % 7, tile = bid / 7;
  int nb = tile & 3, mb = tile >> 2;
  int t = threadIdx.x;
  int w = t >> 6, l = t & 63, lr = l & 15, lh = l >> 4;
  int sr = t >> 2, sq = t & 3;
  f32x4 acc[4];
  #pragma unroll
  for (int i=0;i<4;i++) acc[i] = (f32x4){0.f,0.f,0.f,0.f};
  const int K = 3136;
  const size_t a_row = (size_t)(mb*64 + sr)*K;
  const size_t b_row = (size_t)(nb*64 + sr)*K;
  for (int kk = s*14; kk < s*14 + 14; kk++){
    uint4v av = *(const uint4v*)&A[a_row + kk*32 + sq*8];
    uint4v bv = *(const uint4v*)&B[b_row + kk*32 + sq*8];
    __syncthreads();
    *(uint4v*)((char*)As + ((sr*64 + sq*16) ^ ((sr&3)<<4))) = av;
    *(uint4v*)((char*)Bs + ((sr*64 + sq*16) ^ ((sr&3)<<4))) = bv;
    __syncthreads();
    int brow = w*16 + lr;
    bf16x8 bfr = *(const bf16x8*)((char*)Bs + ((brow*64 + lh*16) ^ ((brow&3)<<4)));
    #pragma unroll
    for (int mt=0;mt<4;mt++){
      int arow = mt*16 + lr;
      bf16x8 afr = *(const bf16x8*)((char*)As + ((arow*64 + lh*16) ^ ((arow&3)<<4)));
      acc[mt] = MFMA16(afr, bfr, acc[mt]);
    }
  }
  int col = nb*64 + w*16 + lr;
  #pragma unroll
  for (int mt=0;mt<4;mt++){
    #pragma unroll
    for (int r=0;r<4;r++){
      int row = mb*64 + mt*16 + lh*4 + r;
      P[(size_t)s*65536 + row*256 + col] = acc[mt][r];
    }
  }
}

// ---------------- FC reduce: sum 7 partials + bias + relu -> nemb node-0 rows ----
__global__ __launch_bounds__(256) void fc_red_k(const float* __restrict__ P,
              const float* __restrict__ fcb, unsigned short* __restrict__ nemb){
  int idx = blockIdx.x*256 + threadIdx.x;       // 65536 total
  int row = idx >> 8, col = idx & 255;
  float sum = fcb[col];
  #pragma unroll
  for (int k=0;k<7;k++) sum += P[k*65536 + idx];
  nemb[(size_t)row*25*256 + col] = f2bf(fmaxf(sum, 0.f));
}

// ---------------- fused MLP+GRU persistent kernel (v10: full reg budget + deep unroll) --
// 192 blocks x 1024 threads (16 waves, exactly 4/EU); block owns 32 rows; wave owns 16 cols.
// Scaling: weights fp8(16w), activations fp8(16a) -> acc * (1/256) before biases.
// fp8 tile swizzle: byte = (row*256 + col) ^ ((row&15)<<3)
__global__ __launch_bounds__(1024, 4) __attribute__((amdgpu_waves_per_eu(4,4)))
void gru_k(const float* __restrict__ obs,
              const unsigned char* __restrict__ wfrag8,
              const unsigned short* __restrict__ mlpfrag,
              const float* __restrict__ mlpb,
              const float* __restrict__ bih, const float* __restrict__ bhh,
              unsigned short* __restrict__ nemb){
  __shared__ __align__(16) unsigned short obsA[1024];   // bf16 [32][32], swz ^((row&3)<<4)
  __shared__ __align__(16) unsigned char e8_0[8192];    // fp8 [32][256], swz ^((m&15)<<3)
  __shared__ __align__(16) unsigned char e8_1[8192];
  __shared__ __align__(16) unsigned char h8[8192];
  __shared__ char lds_pad[60000];                       // force 1 block/CU (>80KB LDS)

  const int t = threadIdx.x, blk = blockIdx.x;
  if (blk == 0x7fffffff) ((volatile char*)lds_pad)[t] = 1;   // keep pad alive
  obsA[t & 1023] = 0;                       // zero incl. k>=16 pad (stays zero)
  for (int j = t; j < 8192; j += 1024) h8[j] = 0;

  const int w = t >> 6, l = t & 63, lr = l & 15, lh = l >> 4;
  const int jcol = w*16 + lr;
  const float bR  = bih[jcol]     + bhh[jcol];
  const float bZ  = bih[256+jcol] + bhh[256+jcol];
  const float bXN = bih[512+jcol];
  const float bHN = bhh[512+jcol];
  const float bMb = mlpb[jcol];
  const bf16x8 bMLP = *(const bf16x8*)(mlpfrag + w*512 + l*8);

  const unsigned char* wb8 = wfrag8 + w*24576 + l*16;

  // obs stage: 128 threads, float4 each. row = t>>2, k4 = t&3
  const int srow = t >> 2, sk4 = t & 3;
  int rrS = blk*32 + srow; int bS = rrS/24, ndS = 1 + (rrS - bS*24);
  const float* obase4 = obs + (size_t)(bS*25 + ndS)*800 + sk4*4;
  const int obyte = (srow*64 + sk4*8) ^ ((srow&3)<<4);

  const int a8off = lr*256 + lh*8;   // fp8 A-frag base (row=lr)
  const int xr8 = lr << 3;           // full-row swizzle (row&15 == lr for both m-tiles)
  const int o16 = lh*16;
  const int oa0b = (lr*64 + o16) ^ ((lr&3)<<4);
  const int oa1b = ((16+lr)*64 + o16) ^ ((lr&3)<<4);
  const int hw0 = jcol;              // h8/e8 write col
  const float S = 1.f/256.f;

  f32x4 hs0 = (f32x4){0.f,0.f,0.f,0.f};   // h state rows lh*4+r, col jcol
  f32x4 hs1 = (f32x4){0.f,0.f,0.f,0.f};   // rows 16+lh*4+r

#define EMB_COMPUTE(DST) { \
  f32x4 e0 = (f32x4){0.f,0.f,0.f,0.f}, e1 = (f32x4){0.f,0.f,0.f,0.f}; \
  bf16x8 oa0 = *(const bf16x8*)((char*)obsA + oa0b); \
  bf16x8 oa1 = *(const bf16x8*)((char*)obsA + oa1b); \
  e0 = MFMA16(oa0, bMLP, e0); \
  e1 = MFMA16(oa1, bMLP, e1); \
  _Pragma("unroll") \
  for (int r=0;r<4;r++){ \
    int m = lh*4 + r; \
    (DST)[(m*256 + hw0) ^ ((m&15)<<3)] = f2fp8(fmaxf(e0[r] + bMb, 0.f)*16.f); \
    int m2 = m + 16; \
    (DST)[(m2*256 + hw0) ^ ((m2&15)<<3)] = f2fp8(fmaxf(e1[r] + bMb, 0.f)*16.f); \
  } }

  // ---- prologue: stage obs(0), emb(0) -> e8_0 ----
  __syncthreads();
  if (t < 128){
    float4v ov = *(const float4v*)(obase4);
    uint2v pk;
    pk[0] = (unsigned)f2bf(ov[0]) | ((unsigned)f2bf(ov[1]) << 16);
    pk[1] = (unsigned)f2bf(ov[2]) | ((unsigned)f2bf(ov[3]) << 16);
    *(uint2v*)((char*)obsA + obyte) = pk;
  }
  __syncthreads();
  EMB_COMPUTE(e8_0)
  __syncthreads();

  for (int step=0; step<50; step++){
    const unsigned char* ebuf = (step & 1) ? e8_1 : e8_0;
    unsigned char* nbuf = (step & 1) ? e8_0 : e8_1;
    const bool stg = (t < 128) && (step < 49);
    // ---- phase 1: issue obs(t+1) loads, main fp8 GEMM(t), write obsA ----
    float4v ov;
    if (stg) ov = *(const float4v*)(obase4 + (size_t)(step+1)*16);

    f32x4 aR0=(f32x4){0,0,0,0}, aR1=(f32x4){0,0,0,0};
    f32x4 aZ0=(f32x4){0,0,0,0}, aZ1=(f32x4){0,0,0,0};
    f32x4 aN0=(f32x4){0,0,0,0}, aN1=(f32x4){0,0,0,0};   // xn part
    f32x4 aM0=(f32x4){0,0,0,0}, aM1=(f32x4){0,0,0,0};   // hn part
    __builtin_amdgcn_s_setprio(1);
    #pragma unroll
    for (int kkp=0;kkp<4;kkp++){
      const unsigned char* wk8 = wb8 + kkp*6144;
      long2v wIR = *(const long2v*)(wk8);
      long2v wIZ = *(const long2v*)(wk8 + 1024);
      long2v wIN = *(const long2v*)(wk8 + 2048);
      long2v wHR = *(const long2v*)(wk8 + 3072);
      long2v wHZ = *(const long2v*)(wk8 + 4096);
      long2v wHN = *(const long2v*)(wk8 + 5120);
      {
        int kk = kkp*2;
        int ab = a8off + kk*32;
        long eA0 = *(const long*)(ebuf + (ab ^ xr8));
        long eA1 = *(const long*)(ebuf + ((ab + 4096) ^ xr8));
        long hA0 = *(const long*)(h8 + (ab ^ xr8));
        long hA1 = *(const long*)(h8 + ((ab + 4096) ^ xr8));
        aR0 = MFMA8(eA0, wIR[0], aR0);  aR0 = MFMA8(hA0, wHR[0], aR0);
        aR1 = MFMA8(eA1, wIR[0], aR1);  aR1 = MFMA8(hA1, wHR[0], aR1);
        aZ0 = MFMA8(eA0, wIZ[0], aZ0);  aZ0 = MFMA8(hA0, wHZ[0], aZ0);
        aZ1 = MFMA8(eA1, wIZ[0], aZ1);  aZ1 = MFMA8(hA1, wHZ[0], aZ1);
        aN0 = MFMA8(eA0, wIN[0], aN0);  aN1 = MFMA8(eA1, wIN[0], aN1);
        aM0 = MFMA8(hA0, wHN[0], aM0);  aM1 = MFMA8(hA1, wHN[0], aM1);
      }
      {
        int kk = kkp*2 + 1;
        int ab = a8off + kk*32;
        long eA0 = *(const long*)(ebuf + (ab ^ xr8));
        long eA1 = *(const long*)(ebuf + ((ab + 4096) ^ xr8));
        long hA0 = *(const long*)(h8 + (ab ^ xr8));
        long hA1 = *(const long*)(h8 + ((ab + 4096) ^ xr8));
        aR0 = MFMA8(eA0, wIR[1], aR0);  aR0 = MFMA8(hA0, wHR[1], aR0);
        aR1 = MFMA8(eA1, wIR[1], aR1);  aR1 = MFMA8(hA1, wHR[1], aR1);
        aZ0 = MFMA8(eA0, wIZ[1], aZ0);  aZ0 = MFMA8(hA0, wHZ[1], aZ0);
        aZ1 = MFMA8(eA1, wIZ[1], aZ1);  aZ1 = MFMA8(hA1, wHZ[1], aZ1);
        aN0 = MFMA8(eA0, wIN[1], aN0);  aN1 = MFMA8(eA1, wIN[1], aN1);
        aM0 = MFMA8(hA0, wHN[1], aM0);  aM1 = MFMA8(hA1, wHN[1], aM1);
      }
    }
    __builtin_amdgcn_s_setprio(0);
    if (stg){
      uint2v pk;
      pk[0] = (unsigned)f2bf(ov[0]) | ((unsigned)f2bf(ov[1]) << 16);
      pk[1] = (unsigned)f2bf(ov[2]) | ((unsigned)f2bf(ov[3]) << 16);
      *(uint2v*)((char*)obsA + obyte) = pk;
    }
    __syncthreads();   // GEMM LDS reads done; obsA(t+1) visible
    // ---- phase 2: emb(t+1) (MFMA) + gate update (VALU, h in f32 regs) ----
    if (step < 49){
      EMB_COMPUTE(nbuf)
    }
    #pragma unroll
    for (int mt=0;mt<2;mt++){
      f32x4 vR = mt ? aR1 : aR0;
      f32x4 vZ = mt ? aZ1 : aZ0;
      f32x4 vN = mt ? aN1 : aN0;
      f32x4 vM = mt ? aM1 : aM0;
      #pragma unroll
      for (int r=0;r<4;r++){
        float rp = vR[r]*S + bR;
        float zp = vZ[r]*S + bZ;
        float xn = vN[r]*S + bXN;
        float hn = vM[r]*S + bHN;
        float rg = 1.f/(1.f + __expf(-rp));
        float zg = 1.f/(1.f + __expf(-zp));
        float arg = xn + rg*hn;
        float e2 = __expf(2.f*arg);
        float nv = (e2 - 1.f)/(e2 + 1.f);
        float hold = mt ? hs1[r] : hs0[r];
        float hnew = (1.f - zg)*nv + zg*hold;
        if (mt) hs1[r] = hnew; else hs0[r] = hnew;
        int m = mt*16 + lh*4 + r;
        h8[(m*256 + hw0) ^ ((m&15)<<3)] = f2fp8(hnew*16.f);
        if (step == 49){
          int rr = blk*32 + m; int b = rr/24; int nd = 1 + (rr - b*24);
          nemb[(size_t)(b*25+nd)*256 + jcol] = f2bf(hnew);
        }
      }
    }
    __syncthreads();   // h8(t) + e8(t+1) visible for next main GEMM
  }
#undef EMB_COMPUTE
}

// ---------------- GAT scores + softmax + node0 out + dueling head ----------------
__global__ __launch_bounds__(256) void gat_k(const int* __restrict__ edges,
              const unsigned short* __restrict__ glgr,
              const float* __restrict__ att, const float* __restrict__ gbias,
              const float* __restrict__ hidw, const float* __restrict__ hidb,
              const float* __restrict__ outw, const float* __restrict__ outb,
              const float* __restrict__ advw, const float* __restrict__ advb,
              float* __restrict__ out){
  __shared__ int src_s[125], dst_s[125];
  __shared__ __align__(16) float att_s[1280];
  __shared__ float sc[125][5], al[125][5];
  __shared__ float mx[25][5], dn[25][5];
  __shared__ float g0[256], hh[256];
  __shared__ float adv_s[8], v_s;
  __shared__ int e0[125]; __shared__ int ne0;

  int b = blockIdx.x, t = threadIdx.x;
  if (t < 100){ src_s[t] = edges[b*200 + t]; dst_s[t] = edges[b*200 + 100 + t]; }
  else if (t < 125){ src_s[t] = t - 100; dst_s[t] = t - 100; }
  for (int j = t; j < 1280; j += 256) att_s[j] = att[j];
  __syncthreads();
  if (t == 0){ int c = 0; for (int e=0;e<125;e++) if (dst_s[e]==0) e0[c++]=e; ne0 = c; }
  const unsigned short* gbase = glgr + (size_t)b*25*2560;
  for (int p = t; p < 625; p += 256){
    int e = p/5, h = p - 5*(p/5);
    const unsigned short* glp = gbase + src_s[e]*2560 + h*256;
    const unsigned short* grp = gbase + dst_s[e]*2560 + 1280 + h*256;
    const float* ap = &att_s[h*256];
    float acc = 0.f;
    #pragma unroll 4
    for (int c=0;c<256;c+=8){
      uint4v gu = *(const uint4v*)&glp[c];
      uint4v ru = *(const uint4v*)&grp[c];
      #pragma unroll
      for (int q=0;q<4;q++){
        float s0 = bflo(gu[q]) + bflo(ru[q]);
        float s1 = bfhi(gu[q]) + bfhi(ru[q]);
        s0 = (s0 > 0.f) ? s0 : 0.2f*s0;
        s1 = (s1 > 0.f) ? s1 : 0.2f*s1;
        acc += s0*ap[c+2*q] + s1*ap[c+2*q+1];
      }
    }
    sc[e][h] = acc;
  }
  __syncthreads();
  if (t < 125){
    int j = t/5, h = t - 5*(t/5);
    float m = -1e30f;
    for (int e=0;e<125;e++) if (dst_s[e]==j) m = fmaxf(m, sc[e][h]);
    float d = 0.f;
    for (int e=0;e<125;e++) if (dst_s[e]==j) d += __expf(sc[e][h]-m);
    mx[j][h] = m; dn[j][h] = d;
  }
  __syncthreads();
  for (int p = t; p < 625; p += 256){
    int e = p/5, h = p - 5*(p/5);
    int dd = dst_s[e];
    al[e][h] = __expf(sc[e][h] - mx[dd][h]) / dn[dd][h];
  }
  __syncthreads();
  if (t < 101){
    out[2048 + b*101 + t] = (al[t][0]+al[t][1]+al[t][2]+al[t][3]+al[t][4])*0.2f;
  }
  {
    float acc = 0.f;
    for (int x=0;x<ne0;x++){
      int e = e0[x]; int s = src_s[e];
      const unsigned short* glp = gbase + s*2560 + t;
      #pragma unroll
      for (int h=0;h<5;h++) acc += al[e][h]*bf2f(glp[h*256]);
    }
    g0[t] = acc*0.2f + gbias[t];
  }
  __syncthreads();
  {
    float acc = hidb[t];
    for (int k=0;k<256;k++) acc += g0[k]*hidw[k*256+t];
    hh[t] = fmaxf(acc, 0.f);
  }
  __syncthreads();
  if (t < 8){
    float acc = advb[t];
    for (int k=0;k<256;k++) acc += hh[k]*advw[k*8+t];
    adv_s[t] = acc;
  } else if (t == 8){
    float acc = outb[0];
    for (int k=0;k<256;k++) acc += hh[k]*outw[k];
    v_s = acc;
  }
  __syncthreads();
  if (t < 8){
    float m = adv_s[0]+adv_s[1]+adv_s[2]+adv_s[3]+adv_s[4]+adv_s[5]+adv_s[6]+adv_s[7];
    out[b*8+t] = v_s + adv_s[t] - m*0.125f;
  }
}

extern "C" void kernel_launch(void* const* d_in, const int* in_sizes, int n_in,
                              void* d_out, int out_size, void* d_ws, size_t ws_size,
                              hipStream_t stream){
  const float* obs     = (const float*)d_in[0];
  const float* obs_map = (const float*)d_in[1];
  const int*   edges   = (const int*)d_in[2];
  const float* mlp_w = (const float*)d_in[4];
  const float* mlp_b = (const float*)d_in[5];
  const float* c1w = (const float*)d_in[6];  const float* c1b = (const float*)d_in[7];
  const float* c2w = (const float*)d_in[8];  const float* c2b = (const float*)d_in[9];
  const float* c3w = (const float*)d_in[10]; const float* c3b = (const float*)d_in[11];
  const float* fcw = (const float*)d_in[12]; const float* fcb = (const float*)d_in[13];
  const float* wih = (const float*)d_in[14]; const float* whh = (const float*)d_in[15];
  const float* bih = (const float*)d_in[16]; const float* bhh = (const float*)d_in[17];
  const float* gwl = (const float*)d_in[18]; const float* gbl = (const float*)d_in[19];
  const float* gwr = (const float*)d_in[20]; const float* gbr = (const float*)d_in[21];
  const float* gatt = (const float*)d_in[22]; const float* gbias = (const float*)d_in[23];
  const float* hidw = (const float*)d_in[24]; const float* hidb = (const float*)d_in[25];
  const float* outw = (const float*)d_in[26]; const float* outb = (const float*)d_in[27];
  const float* advw = (const float*)d_in[28]; const float* advb = (const float*)d_in[29];
  float* out = (float*)d_out;
  char* ws = (char*)d_ws;

  // workspace layout (conv buffers + fcpart aliased under glgr; consumed before glgr write)
  unsigned short* c1o  = (unsigned short*)(ws + 0);          // 6,553,600 B
  unsigned short* c2o  = (unsigned short*)(ws + 6553600);    // 2,654,208 B
  unsigned short* c3o  = (unsigned short*)(ws + 9207808);    // 1,605,632 B
  float*          fcpart = (float*)(ws + 16000000);          // 1,835,008 B (inside glgr window)
  unsigned short* glgr = (unsigned short*)(ws + 0);          // 32,768,000 B
  size_t o = 32768000;
  unsigned short* nemb    = (unsigned short*)(ws + o); o += 3276800;
  unsigned char*  wfrag8  = (unsigned char*)(ws + o);  o += 393216;
  unsigned short* mlpfrag = (unsigned short*)(ws + o); o += 16384;
  unsigned short* wlrT    = (unsigned short*)(ws + o); o += 1310720;
  unsigned short* fcwT    = (unsigned short*)(ws + o); o += 1605632;
  float* blbr             = (float*)(ws + o); o += 10240;

  prep_k<<<7274, 256, 0, stream>>>(wih, whh, gwl, gwr, gbl, gbr, fcw, mlp_w, wfrag8, mlpfrag, wlrT, fcwT, blbr);
  conv1_k<<<1024, 256, 0, stream>>>(obs_map, c1w, c1b, c1o);
  conv2_k<<<1024, 256, 0, stream>>>(c1o, c2w, c2b, c2o);
  conv3_k<<<1024, 256, 0, stream>>>(c2o, c3w, c3b, c3o);
  gemm_fc_k<<<112, 256, 0, stream>>>(c3o, fcwT, fcpart);                          // FC split-K
  fc_red_k<<<256, 256, 0, stream>>>(fcpart, fcb, nemb);                           // -> node 0
  gru_k<<<192, 1024, 0, stream>>>(obs, wfrag8, mlpfrag, mlp_b, bih, bhh, nemb);   // nodes 1..24
  gemm_k<<<4000, 256, 0, stream>>>(nemb, wlrT, blbr, glgr, 256, 2560, 1, 0, 40);  // gl|gr
  gat_k<<<256, 256, 0, stream>>>(edges, glgr, gatt, gbias, hidw, hidb, outw, outb, advw, advb, out);
}

// Round 11
// 728.789 us; speedup vs baseline: 1.5995x; 1.5995x over previous
//
#include <hip/hip_runtime.h>
#include <cstdint>

typedef __attribute__((ext_vector_type(8))) __bf16 bf16x8;
typedef __attribute__((ext_vector_type(4))) float f32x4;
typedef __attribute__((ext_vector_type(4))) unsigned int uint4v;
typedef __attribute__((ext_vector_type(2))) unsigned int uint2v;
typedef __attribute__((ext_vector_type(4))) float float4v;
typedef __attribute__((ext_vector_type(2))) long long2v;

__device__ __forceinline__ unsigned short f2bf(float x){
  union { float f; unsigned u; } v; v.f = x;
  unsigned r = v.u + 0x7FFFu + ((v.u >> 16) & 1u);
  return (unsigned short)(r >> 16);
}
__device__ __forceinline__ float bf2f(unsigned short h){
  union { unsigned u; float f; } v; v.u = ((unsigned)h) << 16;
  return v.f;
}
__device__ __forceinline__ float bflo(unsigned u){
  union { unsigned x; float f; } v; v.x = u << 16; return v.f;
}
__device__ __forceinline__ float bfhi(unsigned u){
  union { unsigned x; float f; } v; v.x = u & 0xFFFF0000u; return v.f;
}
__device__ __forceinline__ f32x4 MFMA16(bf16x8 a, bf16x8 b, f32x4 c){
  return __builtin_amdgcn_mfma_f32_16x16x32_bf16(a, b, c, 0, 0, 0);
}
__device__ __forceinline__ f32x4 MFMA8(long a, long b, f32x4 c){
  return __builtin_amdgcn_mfma_f32_16x16x32_fp8_fp8(a, b, c, 0, 0, 0);
}
__device__ __forceinline__ unsigned char f2fp8(float x){
  int p = __builtin_amdgcn_cvt_pk_fp8_f32(x, x, 0, false);
  return (unsigned char)(p & 0xFF);
}

// ---------------- prep ----------------
// wfrag8 (fp8 e4m3, value = fp8(16*W)): byte idx = (((w*4+kkp)*6+mg)*64 + l)*16 + ks*8 + e
//   kk = kkp*2+ks ; mg: 0=ihR 1=ihZ 2=ihN 3=hhR 4=hhZ 5=hhN
//   n = g*256 + w*16 + (l&15), k = kk*32 + (l>>4)*8 + e
// mlpfrag bf16: idx = w*512 + l*8 + e; n = w*16+(l&15), k = (l>>4)*8+e (k>=16 -> 0)
__global__ __launch_bounds__(256) void prep_k(
    const float* __restrict__ wih, const float* __restrict__ whh,
    const float* __restrict__ wl, const float* __restrict__ wr,
    const float* __restrict__ bl, const float* __restrict__ br,
    const float* __restrict__ fcw, const float* __restrict__ mlpw,
    unsigned char* __restrict__ wfrag8, unsigned short* __restrict__ mlpfrag,
    unsigned short* __restrict__ wlrT, unsigned short* __restrict__ fcwT,
    float* __restrict__ blbr){
  int i = blockIdx.x*256 + threadIdx.x;
  if (i < 393216){
    int b16 = i & 15;
    int l   = (i >> 4) & 63;
    int chunk = i >> 10;           // (w*4+kkp)*6+mg
    int wkp = chunk / 6;
    int mg  = chunk - 6*wkp;
    int w = wkp >> 2, kkp = wkp & 3;
    int ks = b16 >> 3, e = b16 & 7;
    int kk = kkp*2 + ks;
    int mat = mg / 3, g = mg - 3*(mg/3);
    int n = g*256 + w*16 + (l & 15);
    int k = kk*32 + (l >> 4)*8 + e;
    float v = 16.f * (mat ? whh[n*256 + k] : wih[n*256 + k]);
    wfrag8[i] = f2fp8(v);
    return;
  }
  i -= 393216;
  if (i < 8192){
    int w = i >> 9;
    int r4 = i & 511;
    int l = r4 >> 3, e = r4 & 7;
    int n = w*16 + (l & 15);
    int k = (l >> 4)*8 + e;
    mlpfrag[i] = (k < 16) ? f2bf(mlpw[k*256 + n]) : (unsigned short)0;
    return;
  }
  i -= 8192;
  if (i < 655360){
    int n = i >> 8, k = i & 255;
    float v = (n < 1280) ? wl[k*1280 + n] : wr[k*1280 + (n-1280)];
    wlrT[i] = f2bf(v); return;
  }
  i -= 655360;
  if (i < 802816){
    int n = i / 3136, k = i - n*3136;
    fcwT[i] = f2bf(fcw[k*256 + n]); return;
  }
  i -= 802816;
  if (i < 2560){
    blbr[i] = (i < 1280) ? bl[i] : br[i-1280];
  }
}

// ---------------- conv2: bf16 [256,32,20,20] -> bf16 [256,64,9,9], s=2 k=4 ----
__global__ __launch_bounds__(256) void conv2_k(const unsigned short* __restrict__ in,
              const float* __restrict__ w, const float* __restrict__ bias,
              unsigned short* __restrict__ out){
  __shared__ unsigned short in_s[32][20][20];
  __shared__ float w_s[16][32][4][4];
  __shared__ float b_s[16];
  int bid = blockIdx.x; int b = bid >> 2, h = bid & 3;
  int t = threadIdx.x;
  for (int idx = t; idx < 32*400; idx += 256) ((unsigned short*)in_s)[idx] = in[(size_t)b*12800 + idx];
  for (int idx = t; idx < 16*512; idx += 256) ((float*)w_s)[idx] = w[h*8192 + idx];
  if (t < 16) b_s[t] = bias[h*16 + t];
  __syncthreads();
  for (int p = t; p < 432; p += 256){
    int ocl = p / 27; int rem = p - ocl*27;
    int oy = rem / 3, og = rem - oy*3;
    float a0=b_s[ocl],a1=b_s[ocl],a2=b_s[ocl];
    #pragma unroll 4
    for (int ic=0;ic<32;ic++){
      #pragma unroll
      for (int ky=0;ky<4;ky++){
        const unsigned short* row = &in_s[ic][oy*2+ky][og*6];
        float s[8];
        #pragma unroll
        for (int cc=0;cc<8;cc++) s[cc]=bf2f(row[cc]);
        const float* wp = &w_s[ocl][ic][ky][0];
        #pragma unroll
        for (int kx=0;kx<4;kx++){
          float wv = wp[kx];
          a0 += s[kx]*wv; a1 += s[2+kx]*wv; a2 += s[4+kx]*wv;
        }
      }
    }
    size_t ob = ((size_t)(b*64 + h*16+ocl)*9 + oy)*9 + og*3;
    out[ob+0]=f2bf(fmaxf(a0,0.f)); out[ob+1]=f2bf(fmaxf(a1,0.f)); out[ob+2]=f2bf(fmaxf(a2,0.f));
  }
}

// ---------------- conv3: bf16 [256,64,9,9] -> bf16 [256,3136] (flat NCHW), s=1 k=3 ----
__global__ __launch_bounds__(256) void conv3_k(const unsigned short* __restrict__ in,
              const float* __restrict__ w, const float* __restrict__ bias,
              unsigned short* __restrict__ out){
  __shared__ unsigned short in_s[64][9][9];
  __shared__ float w_s[16][64][3][3];
  __shared__ float b_s[16];
  int bid = blockIdx.x; int b = bid >> 2, h = bid & 3;
  int t = threadIdx.x;
  for (int idx = t; idx < 64*81; idx += 256) ((unsigned short*)in_s)[idx] = in[(size_t)b*5184 + idx];
  for (int idx = t; idx < 16*576; idx += 256) ((float*)w_s)[idx] = w[h*9216 + idx];
  if (t < 16) b_s[t] = bias[h*16 + t];
  __syncthreads();
  for (int p = t; p < 224; p += 256){
    int ocl = p / 14; int rem = p - ocl*14;
    int oy = rem >> 1, og = rem & 1;
    int ox0 = og*4; int nx = og ? 3 : 4;
    float a[4]; a[0]=a[1]=a[2]=a[3]=b_s[ocl];
    for (int ic=0;ic<64;ic++){
      #pragma unroll
      for (int ky=0;ky<3;ky++){
        const unsigned short* row = &in_s[ic][oy+ky][ox0];
        float s[6];
        #pragma unroll
        for (int cc=0;cc<6;cc++) s[cc] = (ox0+cc < 9) ? bf2f(row[cc]) : 0.f;
        const float* wp = &w_s[ocl][ic][ky][0];
        #pragma unroll
        for (int kx=0;kx<3;kx++){
          float wv = wp[kx];
          #pragma unroll
          for (int jj=0;jj<4;jj++) a[jj] += s[jj+kx]*wv;
        }
      }
    }
    size_t ob = (size_t)b*3136 + (h*16+ocl)*49 + oy*7 + ox0;
    #pragma unroll
    for (int jj=0;jj<4;jj++) if (jj < nx) out[ob+jj] = f2bf(fmaxf(a[jj],0.f));
  }
}

// ---------------- generic MFMA GEMM: C[m,n] = act(A[m,:]·B[n,:] + bias[n]) ----
__global__ __launch_bounds__(256) void gemm_k(const unsigned short* __restrict__ A,
              const unsigned short* __restrict__ B, const float* __restrict__ bias,
              unsigned short* __restrict__ C, int K, int ldc, int rowmul, int relu, int Nblk){
  __shared__ __align__(16) unsigned short As[64*32];
  __shared__ __align__(16) unsigned short Bs[64*32];
  int bid = blockIdx.x;
  int nb = bid % Nblk, mb = bid / Nblk;
  int t = threadIdx.x;
  int w = t >> 6, l = t & 63, lr = l & 15, lh = l >> 4;
  int sr = t >> 2, sq = t & 3;
  f32x4 acc[4];
  #pragma unroll
  for (int i=0;i<4;i++) acc[i] = (f32x4){0.f,0.f,0.f,0.f};
  int nkk = K >> 5;
  const size_t a_row = (size_t)(mb*64 + sr)*K;
  const size_t b_row = (size_t)(nb*64 + sr)*K;
  for (int kk=0;kk<nkk;kk++){
    uint4v av = *(const uint4v*)&A[a_row + kk*32 + sq*8];
    uint4v bv = *(const uint4v*)&B[b_row + kk*32 + sq*8];
    __syncthreads();
    *(uint4v*)((char*)As + ((sr*64 + sq*16) ^ ((sr&3)<<4))) = av;
    *(uint4v*)((char*)Bs + ((sr*64 + sq*16) ^ ((sr&3)<<4))) = bv;
    __syncthreads();
    int brow = w*16 + lr;
    bf16x8 bfr = *(const bf16x8*)((char*)Bs + ((brow*64 + lh*16) ^ ((brow&3)<<4)));
    #pragma unroll
    for (int mt=0;mt<4;mt++){
      int arow = mt*16 + lr;
      bf16x8 afr = *(const bf16x8*)((char*)As + ((arow*64 + lh*16) ^ ((arow&3)<<4)));
      acc[mt] = MFMA16(afr, bfr, acc[mt]);
    }
  }
  int col = nb*64 + w*16 + lr;
  float bn = bias[col];
  #pragma unroll
  for (int mt=0;mt<4;mt++){
    #pragma unroll
    for (int r=0;r<4;r++){
      int row = mb*64 + mt*16 + lh*4 + r;
      float v = acc[mt][r] + bn;
      if (relu) v = fmaxf(v, 0.f);
      C[(size_t)row*rowmul*ldc + col] = f2bf(v);
    }
  }
}

// ---------------- FC split-K GEMM: 112 blocks = 16 tiles x 7 K-slices, f32 partials ----
__global__ __launch_bounds__(256) void gemm_fc_k(const unsigned short* __restrict__ A,
              const unsigned short* __restrict__ B, float* __restrict__ P){
  __shared__ __align__(16) unsigned short As[64*32];
  __shared__ __align__(16) unsigned short Bs[64*32];
  int bid = blockIdx.x;
  int s = bid % 7, tile = bid / 7;
  int nb = tile & 3, mb = tile >> 2;
  int t = threadIdx.x;
  int w = t >> 6, l = t & 63, lr = l & 15, lh = l >> 4;
  int sr = t >> 2, sq = t & 3;
  f32x4 acc[4];
  #pragma unroll
  for (int i=0;i<4;i++) acc[i] = (f32x4){0.f,0.f,0.f,0.f};
  const int K = 3136;
  const size_t a_row = (size_t)(mb*64 + sr)*K;
  const size_t b_row = (size_t)(nb*64 + sr)*K;
  for (int kk = s*14; kk < s*14 + 14; kk++){
    uint4v av = *(const uint4v*)&A[a_row + kk*32 + sq*8];
    uint4v bv = *(const uint4v*)&B[b_row + kk*32 + sq*8];
    __syncthreads();
    *(uint4v*)((char*)As + ((sr*64 + sq*16) ^ ((sr&3)<<4))) = av;
    *(uint4v*)((char*)Bs + ((sr*64 + sq*16) ^ ((sr&3)<<4))) = bv;
    __syncthreads();
    int brow = w*16 + lr;
    bf16x8 bfr = *(const bf16x8*)((char*)Bs + ((brow*64 + lh*16) ^ ((brow&3)<<4)));
    #pragma unroll
    for (int mt=0;mt<4;mt++){
      int arow = mt*16 + lr;
      bf16x8 afr = *(const bf16x8*)((char*)As + ((arow*64 + lh*16) ^ ((arow&3)<<4)));
      acc[mt] = MFMA16(afr, bfr, acc[mt]);
    }
  }
  int col = nb*64 + w*16 + lr;
  #pragma unroll
  for (int mt=0;mt<4;mt++){
    #pragma unroll
    for (int r=0;r<4;r++){
      int row = mb*64 + mt*16 + lh*4 + r;
      P[(size_t)s*65536 + row*256 + col] = acc[mt][r];
    }
  }
}

// ---------------- FC reduce: sum 7 partials + bias + relu -> nemb node-0 rows ----
__global__ __launch_bounds__(256) void fc_red_k(const float* __restrict__ P,
              const float* __restrict__ fcb, unsigned short* __restrict__ nemb){
  int idx = blockIdx.x*256 + threadIdx.x;       // 65536 total
  int row = idx >> 8, col = idx & 255;
  float sum = fcb[col];
  #pragma unroll
  for (int k=0;k<7;k++) sum += P[k*65536 + idx];
  nemb[(size_t)row*25*256 + col] = f2bf(fmaxf(sum, 0.f));
}

// ---------------- mega kernel: blocks 0..191 = GRU (exact R9); 192..447 = conv1 --------
// GRU: 16 waves, block owns 32 rows, wave owns 16 h-cols; fp8 weights/acts, f32 reg h.
// conv1: block handles batch b=blk-192, 4 strips q=t>>8 (each 256 threads = old conv1 block).
__global__ __launch_bounds__(1024, 4)
void gruconv_k(const float* __restrict__ obs,
              const unsigned char* __restrict__ wfrag8,
              const unsigned short* __restrict__ mlpfrag,
              const float* __restrict__ mlpb,
              const float* __restrict__ bih, const float* __restrict__ bhh,
              unsigned short* __restrict__ nemb,
              const float* __restrict__ cin, const float* __restrict__ c1w,
              const float* __restrict__ c1b, unsigned short* __restrict__ c1o){
  __shared__ __align__(16) char smem[121984];

  const int t = threadIdx.x, blk = blockIdx.x;

  if (blk >= 192){
    // ================= conv1 path =================
    float* in_s = (float*)smem;                     // [4][3][24][84] = 96768 B
    float* w_s  = (float*)(smem + 96768);           // [32][3][8][8]  = 24576 B
    float* b_s  = (float*)(smem + 121344);          // [32]
    int b = blk - 192;
    int q = t >> 8, t2 = t & 255;
    float* inq = in_s + q*6048;
    for (int idx = t2; idx < 3*24*84; idx += 256){
      int ic = idx / (24*84); int rem = idx - ic*(24*84);
      int iy = rem / 84, ix = rem - iy*84;
      inq[idx] = cin[((size_t)(b*3+ic)*84 + (q*20 + iy))*84 + ix];
    }
    for (int idx = t; idx < 32*192; idx += 1024) w_s[idx] = c1w[idx];
    if (t < 32) b_s[t] = c1b[t];
    __syncthreads();
    for (int p = t2; p < 800; p += 256){
      int oc = p / 25; int rem = p - oc*25;
      int oy = rem / 5, og = rem - oy*5;
      float a0=b_s[oc],a1=b_s[oc],a2=b_s[oc],a3=b_s[oc];
      #pragma unroll
      for (int ic=0;ic<3;ic++){
        #pragma unroll
        for (int ky=0;ky<8;ky++){
          const float* row = &inq[(ic*24 + oy*4+ky)*84 + og*16];
          float s[20];
          #pragma unroll
          for (int cc=0;cc<20;cc++) s[cc]=row[cc];
          const float* wp = &w_s[(oc*3 + ic)*64 + ky*8];
          #pragma unroll
          for (int kx=0;kx<8;kx++){
            float wv = wp[kx];
            a0 += s[kx]*wv; a1 += s[4+kx]*wv; a2 += s[8+kx]*wv; a3 += s[12+kx]*wv;
          }
        }
      }
      size_t ob = ((size_t)(b*32+oc)*20 + (q*5+oy))*20 + og*4;
      c1o[ob+0]=f2bf(fmaxf(a0,0.f)); c1o[ob+1]=f2bf(fmaxf(a1,0.f));
      c1o[ob+2]=f2bf(fmaxf(a2,0.f)); c1o[ob+3]=f2bf(fmaxf(a3,0.f));
    }
    return;
  }

  // ================= GRU path (exact R9) =================
  unsigned short* obsA = (unsigned short*)smem;           // bf16 [32][32], swz ^((row&3)<<4)
  unsigned char* e8_0 = (unsigned char*)(smem + 2048);    // fp8 [32][256], swz ^((m&15)<<3)
  unsigned char* e8_1 = (unsigned char*)(smem + 10240);
  unsigned char* h8   = (unsigned char*)(smem + 18432);

  obsA[t & 1023] = 0;                       // zero incl. k>=16 pad (stays zero)
  for (int j = t; j < 8192; j += 1024) h8[j] = 0;

  const int w = t >> 6, l = t & 63, lr = l & 15, lh = l >> 4;
  const int jcol = w*16 + lr;
  const float bR  = bih[jcol]     + bhh[jcol];
  const float bZ  = bih[256+jcol] + bhh[256+jcol];
  const float bXN = bih[512+jcol];
  const float bHN = bhh[512+jcol];
  const float bMb = mlpb[jcol];
  const bf16x8 bMLP = *(const bf16x8*)(mlpfrag + w*512 + l*8);

  const unsigned char* wb8 = wfrag8 + w*24576 + l*16;

  // obs stage: 128 threads, float4 each. row = t>>2, k4 = t&3
  const int srow = t >> 2, sk4 = t & 3;
  int rrS = blk*32 + srow; int bS = rrS/24, ndS = 1 + (rrS - bS*24);
  const float* obase4 = obs + (size_t)(bS*25 + ndS)*800 + sk4*4;
  const int obyte = (srow*64 + sk4*8) ^ ((srow&3)<<4);

  const int a8off = lr*256 + lh*8;   // fp8 A-frag base (row=lr)
  const int xr8 = lr << 3;           // full-row swizzle (row&15 == lr for both m-tiles)
  const int o16 = lh*16;
  const int oa0b = (lr*64 + o16) ^ ((lr&3)<<4);
  const int oa1b = ((16+lr)*64 + o16) ^ ((lr&3)<<4);
  const int hw0 = jcol;              // h8/e8 write col
  const float S = 1.f/256.f;

  f32x4 hs0 = (f32x4){0.f,0.f,0.f,0.f};   // h state rows lh*4+r, col jcol
  f32x4 hs1 = (f32x4){0.f,0.f,0.f,0.f};   // rows 16+lh*4+r

#define EMB_COMPUTE(DST) { \
  f32x4 e0 = (f32x4){0.f,0.f,0.f,0.f}, e1 = (f32x4){0.f,0.f,0.f,0.f}; \
  bf16x8 oa0 = *(const bf16x8*)((char*)obsA + oa0b); \
  bf16x8 oa1 = *(const bf16x8*)((char*)obsA + oa1b); \
  e0 = MFMA16(oa0, bMLP, e0); \
  e1 = MFMA16(oa1, bMLP, e1); \
  _Pragma("unroll") \
  for (int r=0;r<4;r++){ \
    int m = lh*4 + r; \
    (DST)[(m*256 + hw0) ^ ((m&15)<<3)] = f2fp8(fmaxf(e0[r] + bMb, 0.f)*16.f); \
    int m2 = m + 16; \
    (DST)[(m2*256 + hw0) ^ ((m2&15)<<3)] = f2fp8(fmaxf(e1[r] + bMb, 0.f)*16.f); \
  } }

  // ---- prologue: stage obs(0), emb(0) -> e8_0 ----
  __syncthreads();
  if (t < 128){
    float4v ov = *(const float4v*)(obase4);
    uint2v pk;
    pk[0] = (unsigned)f2bf(ov[0]) | ((unsigned)f2bf(ov[1]) << 16);
    pk[1] = (unsigned)f2bf(ov[2]) | ((unsigned)f2bf(ov[3]) << 16);
    *(uint2v*)((char*)obsA + obyte) = pk;
  }
  __syncthreads();
  EMB_COMPUTE(e8_0)
  __syncthreads();

  for (int step=0; step<50; step++){
    const unsigned char* ebuf = (step & 1) ? e8_1 : e8_0;
    unsigned char* nbuf = (step & 1) ? e8_0 : e8_1;
    const bool stg = (t < 128) && (step < 49);
    // ---- phase 1: issue obs(t+1) loads, main fp8 GEMM(t), write obsA ----
    float4v ov;
    if (stg) ov = *(const float4v*)(obase4 + (size_t)(step+1)*16);

    f32x4 aR0=(f32x4){0,0,0,0}, aR1=(f32x4){0,0,0,0};
    f32x4 aZ0=(f32x4){0,0,0,0}, aZ1=(f32x4){0,0,0,0};
    f32x4 aN0=(f32x4){0,0,0,0}, aN1=(f32x4){0,0,0,0};   // xn part
    f32x4 aM0=(f32x4){0,0,0,0}, aM1=(f32x4){0,0,0,0};   // hn part
    __builtin_amdgcn_s_setprio(1);
    #pragma unroll 2
    for (int kkp=0;kkp<4;kkp++){
      const unsigned char* wk8 = wb8 + kkp*6144;
      long2v wIR = *(const long2v*)(wk8);
      long2v wIZ = *(const long2v*)(wk8 + 1024);
      long2v wIN = *(const long2v*)(wk8 + 2048);
      long2v wHR = *(const long2v*)(wk8 + 3072);
      long2v wHZ = *(const long2v*)(wk8 + 4096);
      long2v wHN = *(const long2v*)(wk8 + 5120);
      {
        int kk = kkp*2;
        int ab = a8off + kk*32;
        long eA0 = *(const long*)(ebuf + (ab ^ xr8));
        long eA1 = *(const long*)(ebuf + ((ab + 4096) ^ xr8));
        long hA0 = *(const long*)(h8 + (ab ^ xr8));
        long hA1 = *(const long*)(h8 + ((ab + 4096) ^ xr8));
        aR0 = MFMA8(eA0, wIR[0], aR0);  aR0 = MFMA8(hA0, wHR[0], aR0);
        aR1 = MFMA8(eA1, wIR[0], aR1);  aR1 = MFMA8(hA1, wHR[0], aR1);
        aZ0 = MFMA8(eA0, wIZ[0], aZ0);  aZ0 = MFMA8(hA0, wHZ[0], aZ0);
        aZ1 = MFMA8(eA1, wIZ[0], aZ1);  aZ1 = MFMA8(hA1, wHZ[0], aZ1);
        aN0 = MFMA8(eA0, wIN[0], aN0);  aN1 = MFMA8(eA1, wIN[0], aN1);
        aM0 = MFMA8(hA0, wHN[0], aM0);  aM1 = MFMA8(hA1, wHN[0], aM1);
      }
      {
        int kk = kkp*2 + 1;
        int ab = a8off + kk*32;
        long eA0 = *(const long*)(ebuf + (ab ^ xr8));
        long eA1 = *(const long*)(ebuf + ((ab + 4096) ^ xr8));
        long hA0 = *(const long*)(h8 + (ab ^ xr8));
        long hA1 = *(const long*)(h8 + ((ab + 4096) ^ xr8));
        aR0 = MFMA8(eA0, wIR[1], aR0);  aR0 = MFMA8(hA0, wHR[1], aR0);
        aR1 = MFMA8(eA1, wIR[1], aR1);  aR1 = MFMA8(hA1, wHR[1], aR1);
        aZ0 = MFMA8(eA0, wIZ[1], aZ0);  aZ0 = MFMA8(hA0, wHZ[1], aZ0);
        aZ1 = MFMA8(eA1, wIZ[1], aZ1);  aZ1 = MFMA8(hA1, wHZ[1], aZ1);
        aN0 = MFMA8(eA0, wIN[1], aN0);  aN1 = MFMA8(eA1, wIN[1], aN1);
        aM0 = MFMA8(hA0, wHN[1], aM0);  aM1 = MFMA8(hA1, wHN[1], aM1);
      }
    }
    __builtin_amdgcn_s_setprio(0);
    if (stg){
      uint2v pk;
      pk[0] = (unsigned)f2bf(ov[0]) | ((unsigned)f2bf(ov[1]) << 16);
      pk[1] = (unsigned)f2bf(ov[2]) | ((unsigned)f2bf(ov[3]) << 16);
      *(uint2v*)((char*)obsA + obyte) = pk;
    }
    __syncthreads();   // GEMM LDS reads done; obsA(t+1) visible
    // ---- phase 2: emb(t+1) (MFMA) + gate update (VALU, h in f32 regs) ----
    if (step < 49){
      EMB_COMPUTE(nbuf)
    }
    #pragma unroll
    for (int mt=0;mt<2;mt++){
      f32x4 vR = mt ? aR1 : aR0;
      f32x4 vZ = mt ? aZ1 : aZ0;
      f32x4 vN = mt ? aN1 : aN0;
      f32x4 vM = mt ? aM1 : aM0;
      #pragma unroll
      for (int r=0;r<4;r++){
        float rp = vR[r]*S + bR;
        float zp = vZ[r]*S + bZ;
        float xn = vN[r]*S + bXN;
        float hn = vM[r]*S + bHN;
        float rg = 1.f/(1.f + __expf(-rp));
        float zg = 1.f/(1.f + __expf(-zp));
        float arg = xn + rg*hn;
        float e2 = __expf(2.f*arg);
        float nv = (e2 - 1.f)/(e2 + 1.f);
        float hold = mt ? hs1[r] : hs0[r];
        float hnew = (1.f - zg)*nv + zg*hold;
        if (mt) hs1[r] = hnew; else hs0[r] = hnew;
        int m = mt*16 + lh*4 + r;
        h8[(m*256 + hw0) ^ ((m&15)<<3)] = f2fp8(hnew*16.f);
        if (step == 49){
          int rr = blk*32 + m; int b = rr/24; int nd = 1 + (rr - b*24);
          nemb[(size_t)(b*25+nd)*256 + jcol] = f2bf(hnew);
        }
      }
    }
    __syncthreads();   // h8(t) + e8(t+1) visible for next main GEMM
  }
#undef EMB_COMPUTE
}

// ---------------- GAT scores + softmax + node0 out + dueling head ----------------
__global__ __launch_bounds__(256) void gat_k(const int* __restrict__ edges,
              const unsigned short* __restrict__ glgr,
              const float* __restrict__ att, const float* __restrict__ gbias,
              const float* __restrict__ hidw, const float* __restrict__ hidb,
              const float* __restrict__ outw, const float* __restrict__ outb,
              const float* __restrict__ advw, const float* __restrict__ advb,
              float* __restrict__ out){
  __shared__ int src_s[125], dst_s[125];
  __shared__ __align__(16) float att_s[1280];
  __shared__ float sc[125][5], al[125][5];
  __shared__ float mx[25][5], dn[25][5];
  __shared__ float g0[256], hh[256];
  __shared__ float adv_s[8], v_s;
  __shared__ int e0[125]; __shared__ int ne0;

  int b = blockIdx.x, t = threadIdx.x;
  if (t < 100){ src_s[t] = edges[b*200 + t]; dst_s[t] = edges[b*200 + 100 + t]; }
  else if (t < 125){ src_s[t] = t - 100; dst_s[t] = t - 100; }
  for (int j = t; j < 1280; j += 256) att_s[j] = att[j];
  __syncthreads();
  if (t == 0){ int c = 0; for (int e=0;e<125;e++) if (dst_s[e]==0) e0[c++]=e; ne0 = c; }
  const unsigned short* gbase = glgr + (size_t)b*25*2560;
  for (int p = t; p < 625; p += 256){
    int e = p/5, h = p - 5*(p/5);
    const unsigned short* glp = gbase + src_s[e]*2560 + h*256;
    const unsigned short* grp = gbase + dst_s[e]*2560 + 1280 + h*256;
    const float* ap = &att_s[h*256];
    float acc = 0.f;
    #pragma unroll 4
    for (int c=0;c<256;c+=8){
      uint4v gu = *(const uint4v*)&glp[c];
      uint4v ru = *(const uint4v*)&grp[c];
      #pragma unroll
      for (int q=0;q<4;q++){
        float s0 = bflo(gu[q]) + bflo(ru[q]);
        float s1 = bfhi(gu[q]) + bfhi(ru[q]);
        s0 = (s0 > 0.f) ? s0 : 0.2f*s0;
        s1 = (s1 > 0.f) ? s1 : 0.2f*s1;
        acc += s0*ap[c+2*q] + s1*ap[c+2*q+1];
      }
    }
    sc[e][h] = acc;
  }
  __syncthreads();
  if (t < 125){
    int j = t/5, h = t - 5*(t/5);
    float m = -1e30f;
    for (int e=0;e<125;e++) if (dst_s[e]==j) m = fmaxf(m, sc[e][h]);
    float d = 0.f;
    for (int e=0;e<125;e++) if (dst_s[e]==j) d += __expf(sc[e][h]-m);
    mx[j][h] = m; dn[j][h] = d;
  }
  __syncthreads();
  for (int p = t; p < 625; p += 256){
    int e = p/5, h = p - 5*(p/5);
    int dd = dst_s[e];
    al[e][h] = __expf(sc[e][h] - mx[dd][h]) / dn[dd][h];
  }
  __syncthreads();
  if (t < 101){
    out[2048 + b*101 + t] = (al[t][0]+al[t][1]+al[t][2]+al[t][3]+al[t][4])*0.2f;
  }
  {
    float acc = 0.f;
    for (int x=0;x<ne0;x++){
      int e = e0[x]; int s = src_s[e];
      const unsigned short* glp = gbase + s*2560 + t;
      #pragma unroll
      for (int h=0;h<5;h++) acc += al[e][h]*bf2f(glp[h*256]);
    }
    g0[t] = acc*0.2f + gbias[t];
  }
  __syncthreads();
  {
    float acc = hidb[t];
    for (int k=0;k<256;k++) acc += g0[k]*hidw[k*256+t];
    hh[t] = fmaxf(acc, 0.f);
  }
  __syncthreads();
  if (t < 8){
    float acc = advb[t];
    for (int k=0;k<256;k++) acc += hh[k]*advw[k*8+t];
    adv_s[t] = acc;
  } else if (t == 8){
    float acc = outb[0];
    for (int k=0;k<256;k++) acc += hh[k]*outw[k];
    v_s = acc;
  }
  __syncthreads();
  if (t < 8){
    float m = adv_s[0]+adv_s[1]+adv_s[2]+adv_s[3]+adv_s[4]+adv_s[5]+adv_s[6]+adv_s[7];
    out[b*8+t] = v_s + adv_s[t] - m*0.125f;
  }
}

extern "C" void kernel_launch(void* const* d_in, const int* in_sizes, int n_in,
                              void* d_out, int out_size, void* d_ws, size_t ws_size,
                              hipStream_t stream){
  const float* obs     = (const float*)d_in[0];
  const float* obs_map = (const float*)d_in[1];
  const int*   edges   = (const int*)d_in[2];
  const float* mlp_w = (const float*)d_in[4];
  const float* mlp_b = (const float*)d_in[5];
  const float* c1w = (const float*)d_in[6];  const float* c1b = (const float*)d_in[7];
  const float* c2w = (const float*)d_in[8];  const float* c2b = (const float*)d_in[9];
  const float* c3w = (const float*)d_in[10]; const float* c3b = (const float*)d_in[11];
  const float* fcw = (const float*)d_in[12]; const float* fcb = (const float*)d_in[13];
  const float* wih = (const float*)d_in[14]; const float* whh = (const float*)d_in[15];
  const float* bih = (const float*)d_in[16]; const float* bhh = (const float*)d_in[17];
  const float* gwl = (const float*)d_in[18]; const float* gbl = (const float*)d_in[19];
  const float* gwr = (const float*)d_in[20]; const float* gbr = (const float*)d_in[21];
  const float* gatt = (const float*)d_in[22]; const float* gbias = (const float*)d_in[23];
  const float* hidw = (const float*)d_in[24]; const float* hidb = (const float*)d_in[25];
  const float* outw = (const float*)d_in[26]; const float* outb = (const float*)d_in[27];
  const float* advw = (const float*)d_in[28]; const float* advb = (const float*)d_in[29];
  float* out = (float*)d_out;
  char* ws = (char*)d_ws;

  // workspace layout (conv buffers + fcpart aliased under glgr; consumed before glgr write)
  unsigned short* c1o  = (unsigned short*)(ws + 0);          // 6,553,600 B
  unsigned short* c2o  = (unsigned short*)(ws + 6553600);    // 2,654,208 B
  unsigned short* c3o  = (unsigned short*)(ws + 9207808);    // 1,605,632 B
  float*          fcpart = (float*)(ws + 16000000);          // 1,835,008 B (inside glgr window)
  unsigned short* glgr = (unsigned short*)(ws + 0);          // 32,768,000 B
  size_t o = 32768000;
  unsigned short* nemb    = (unsigned short*)(ws + o); o += 3276800;
  unsigned char*  wfrag8  = (unsigned char*)(ws + o);  o += 393216;
  unsigned short* mlpfrag = (unsigned short*)(ws + o); o += 16384;
  unsigned short* wlrT    = (unsigned short*)(ws + o); o += 1310720;
  unsigned short* fcwT    = (unsigned short*)(ws + o); o += 1605632;
  float* blbr             = (float*)(ws + o); o += 10240;

  prep_k<<<7274, 256, 0, stream>>>(wih, whh, gwl, gwr, gbl, gbr, fcw, mlp_w, wfrag8, mlpfrag, wlrT, fcwT, blbr);
  gruconv_k<<<448, 1024, 0, stream>>>(obs, wfrag8, mlpfrag, mlp_b, bih, bhh, nemb,
                                      obs_map, c1w, c1b, c1o);                    // gru + conv1
  conv2_k<<<1024, 256, 0, stream>>>(c1o, c2w, c2b, c2o);
  conv3_k<<<1024, 256, 0, stream>>>(c2o, c3w, c3b, c3o);
  gemm_fc_k<<<112, 256, 0, stream>>>(c3o, fcwT, fcpart);                          // FC split-K
  fc_red_k<<<256, 256, 0, stream>>>(fcpart, fcb, nemb);                           // -> node 0
  gemm_k<<<4000, 256, 0, stream>>>(nemb, wlrT, blbr, glgr, 256, 2560, 1, 0, 40);  // gl|gr
  gat_k<<<256, 256, 0, stream>>>(edges, glgr, gatt, gbias, hidw, hidb, outw, outb, advw, advb, out);
}